// Round 2
// baseline (10575.391 us; speedup 1.0000x reference)
//
#include <hip/hip_runtime.h>
#include <hip/hip_bf16.h>
#include <cstdint>
#include <cstddef>

// ---------------------------------------------------------------------------
// RGCN 3-layer + FC head, fp32 compute, per-relation processing.
// Peak workspace ~251.4 MB with explicit region aliasing:
//   [cnt 0.5MB][region A: h1 (later H3+h3) 163.8MB][region B: A_r / h2 81.9MB]
//   [region C: bf16 H-chunk 5.1MB]
// ---------------------------------------------------------------------------

#define FLAG_ACC  1
#define FLAG_RELU 2
#define FLAG_BF16 4

__global__ __launch_bounds__(256) void zero_kernel(float* __restrict__ p, long n4)
{
    long i = (long)blockIdx.x * 256 + threadIdx.x;
    if (i < n4) ((float4*)p)[i] = make_float4(0.f, 0.f, 0.f, 0.f);
}

__global__ __launch_bounds__(256) void count_kernel(
    const int* __restrict__ dst, const int* __restrict__ et,
    int* __restrict__ cnt, int E)
{
    int e = blockIdx.x * 256 + threadIdx.x;
    if (e < E) atomicAdd(&cnt[dst[e] * 3 + et[e]], 1);
}

// Layer-1 aggregate-first scatter (relation r only): A[dst,c] += x[src,c]*norm.
// A is N x 256. 64 threads per edge (float4 each); whole wave shares one edge.
__global__ __launch_bounds__(256) void scatter1_kernel(
    const float* __restrict__ x, const int* __restrict__ src,
    const int* __restrict__ dst, const int* __restrict__ et,
    const int* __restrict__ cnt, float* __restrict__ A, int E, int r)
{
    long tid = (long)blockIdx.x * 256 + threadIdx.x;
    int e = (int)(tid >> 6);
    if (e >= E || et[e] != r) return;
    int c = (int)(tid & 63);
    int s = src[e], d = dst[e];
    int cv = cnt[d * 3 + r];
    float norm = 1.0f / (float)(cv > 0 ? cv : 1);
    float4 v = *(const float4*)&x[(size_t)s * 256 + c * 4];
    float* o = &A[(size_t)d * 256 + c * 4];
    atomicAdd(o + 0, v.x * norm);
    atomicAdd(o + 1, v.y * norm);
    atomicAdd(o + 2, v.z * norm);
    atomicAdd(o + 3, v.w * norm);
}

// Layer-2 transform-first scatter (relation r, column chunk c0..c0+63):
// h2[dst, c0+c] += bf16(Hc[src, c]) * norm.  Hc is N x 64 bf16.
__global__ __launch_bounds__(256) void scatter2_kernel(
    const __hip_bfloat16* __restrict__ Hc, const int* __restrict__ src,
    const int* __restrict__ dst, const int* __restrict__ et,
    const int* __restrict__ cnt, float* __restrict__ h2, int E, int r, int c0)
{
    long tid = (long)blockIdx.x * 256 + threadIdx.x;
    int e = (int)(tid >> 4);
    if (e >= E || et[e] != r) return;
    int c = (int)(tid & 15);
    int s = src[e], d = dst[e];
    int cv = cnt[d * 3 + r];
    float norm = 1.0f / (float)(cv > 0 ? cv : 1);
    ushort4 raw = *(const ushort4*)&Hc[(size_t)s * 64 + c * 4];
    float* o = &h2[(size_t)d * 512 + c0 + c * 4];
    atomicAdd(o + 0, __uint_as_float((unsigned)raw.x << 16) * norm);
    atomicAdd(o + 1, __uint_as_float((unsigned)raw.y << 16) * norm);
    atomicAdd(o + 2, __uint_as_float((unsigned)raw.z << 16) * norm);
    atomicAdd(o + 3, __uint_as_float((unsigned)raw.w << 16) * norm);
}

// Layer-3 transform-first scatter (relation r): h3[dst,c] += H3[src,c]*norm.
// H3 is N x 128 f32. 32 threads per edge.
__global__ __launch_bounds__(256) void scatter3_kernel(
    const float* __restrict__ H3, const int* __restrict__ src,
    const int* __restrict__ dst, const int* __restrict__ et,
    const int* __restrict__ cnt, float* __restrict__ h3, int E, int r)
{
    long tid = (long)blockIdx.x * 256 + threadIdx.x;
    int e = (int)(tid >> 5);
    if (e >= E || et[e] != r) return;
    int c = (int)(tid & 31);
    int s = src[e], d = dst[e];
    int cv = cnt[d * 3 + r];
    float norm = 1.0f / (float)(cv > 0 ? cv : 1);
    float4 v = *(const float4*)&H3[(size_t)s * 128 + c * 4];
    float* o = &h3[(size_t)d * 128 + c * 4];
    atomicAdd(o + 0, v.x * norm);
    atomicAdd(o + 1, v.y * norm);
    atomicAdd(o + 2, v.z * norm);
    atomicAdd(o + 3, v.w * norm);
}

__global__ __launch_bounds__(256) void relu_kernel(float* __restrict__ p, long n4)
{
    long i = (long)blockIdx.x * 256 + threadIdx.x;
    if (i >= n4) return;
    float4 v = ((float4*)p)[i];
    v.x = fmaxf(v.x, 0.f); v.y = fmaxf(v.y, 0.f);
    v.z = fmaxf(v.z, 0.f); v.w = fmaxf(v.w, 0.f);
    ((float4*)p)[i] = v;
}

// C[M,N] = (flags&ACC ? C : 0) + A[M,K] @ B[K,:, ldb] (+bias) (+relu) (bf16 out opt)
// M%64==0, N%64==0, K%16==0. C row stride = N.
__global__ __launch_bounds__(256) void gemm64(
    const float* __restrict__ A, const float* __restrict__ B,
    const float* __restrict__ bias, void* __restrict__ Cout,
    int M, int N, int K, int ldb, int flags)
{
    __shared__ float As[16][65];
    __shared__ float __align__(16) Bs[16][68];
    const int tid = threadIdx.x;
    const int bx = blockIdx.x, by = blockIdx.y;
    const int row0 = by * 64, col0 = bx * 64;
    const int tx = tid & 15, ty = tid >> 4;
    const int la_r = tid >> 2, la_c = (tid & 3) << 2;   // A tile: 64 rows x 16 cols
    const int lb_r = tid >> 4, lb_c = (tid & 15) << 2;  // B tile: 16 rows x 64 cols
    const float* Aptr = A + (size_t)(row0 + la_r) * K + la_c;
    const float* Bptr = B + (size_t)lb_r * ldb + col0 + lb_c;

    float acc[4][4];
#pragma unroll
    for (int i = 0; i < 4; ++i)
#pragma unroll
        for (int j = 0; j < 4; ++j) acc[i][j] = 0.f;

    for (int k0 = 0; k0 < K; k0 += 16) {
        float4 av = *(const float4*)(Aptr + k0);
        float4 bv = *(const float4*)(Bptr + (size_t)k0 * ldb);
        As[la_c + 0][la_r] = av.x;
        As[la_c + 1][la_r] = av.y;
        As[la_c + 2][la_r] = av.z;
        As[la_c + 3][la_r] = av.w;
        *(float4*)&Bs[lb_r][lb_c] = bv;
        __syncthreads();
#pragma unroll
        for (int k = 0; k < 16; ++k) {
            float a0 = As[k][ty * 4 + 0];
            float a1 = As[k][ty * 4 + 1];
            float a2 = As[k][ty * 4 + 2];
            float a3 = As[k][ty * 4 + 3];
            float b0 = Bs[k][tx * 4 + 0];
            float b1 = Bs[k][tx * 4 + 1];
            float b2 = Bs[k][tx * 4 + 2];
            float b3 = Bs[k][tx * 4 + 3];
            acc[0][0] += a0 * b0; acc[0][1] += a0 * b1; acc[0][2] += a0 * b2; acc[0][3] += a0 * b3;
            acc[1][0] += a1 * b0; acc[1][1] += a1 * b1; acc[1][2] += a1 * b2; acc[1][3] += a1 * b3;
            acc[2][0] += a2 * b0; acc[2][1] += a2 * b1; acc[2][2] += a2 * b2; acc[2][3] += a2 * b3;
            acc[3][0] += a3 * b0; acc[3][1] += a3 * b1; acc[3][2] += a3 * b2; acc[3][3] += a3 * b3;
        }
        __syncthreads();
    }

#pragma unroll
    for (int i = 0; i < 4; ++i) {
        int r = row0 + ty * 4 + i;
#pragma unroll
        for (int j = 0; j < 4; ++j) {
            int c = col0 + tx * 4 + j;
            float v = acc[i][j];
            if (bias) v += bias[c];
            size_t idx = (size_t)r * N + c;
            if (flags & FLAG_BF16) {
                ((__hip_bfloat16*)Cout)[idx] = __float2bfloat16(v);
            } else {
                float* C = (float*)Cout;
                if (flags & FLAG_ACC) v += C[idx];
                if (flags & FLAG_RELU) v = fmaxf(v, 0.f);
                C[idx] = v;
            }
        }
    }
}

// logits = relu(h3) @ fcw + fcb; out = log_softmax(logits). One wave per row.
__global__ __launch_bounds__(256) void head_kernel(
    const float* __restrict__ h3, const float* __restrict__ fcw,
    const float* __restrict__ fcb, float* __restrict__ out, int M)
{
    __shared__ float sh[4][128];
    int wid = threadIdx.x >> 6, lane = threadIdx.x & 63;
    int row = blockIdx.x * 4 + wid;  // grid = M/4 exactly
    sh[wid][lane]      = fmaxf(h3[(size_t)row * 128 + lane], 0.f);
    sh[wid][64 + lane] = fmaxf(h3[(size_t)row * 128 + 64 + lane], 0.f);
    __syncthreads();
    float logit = 0.f;
    if (lane < 21) {
        logit = fcb[lane];
#pragma unroll
        for (int k = 0; k < 128; ++k) logit += sh[wid][k] * fcw[k * 21 + lane];
    }
    float v = (lane < 21) ? logit : -INFINITY;
#pragma unroll
    for (int off = 32; off; off >>= 1) v = fmaxf(v, __shfl_xor(v, off));
    float mx = v;
    float ex = (lane < 21) ? expf(logit - mx) : 0.f;
#pragma unroll
    for (int off = 32; off; off >>= 1) ex += __shfl_xor(ex, off);
    if (lane < 21) out[(size_t)row * 21 + lane] = logit - mx - logf(ex);
}

extern "C" void kernel_launch(void* const* d_in, const int* in_sizes, int n_in,
                              void* d_out, int out_size, void* d_ws, size_t ws_size,
                              hipStream_t stream)
{
    const float* x     = (const float*)d_in[0];
    const int*   ei    = (const int*)d_in[1];
    const int*   etp   = (const int*)d_in[2];
    const float* W1    = (const float*)d_in[3];
    const float* root1 = (const float*)d_in[4];
    const float* b1    = (const float*)d_in[5];
    const float* W2    = (const float*)d_in[6];
    const float* root2 = (const float*)d_in[7];
    const float* b2    = (const float*)d_in[8];
    const float* W3    = (const float*)d_in[9];
    const float* root3 = (const float*)d_in[10];
    const float* b3    = (const float*)d_in[11];
    const float* fcw   = (const float*)d_in[12];
    const float* fcb   = (const float*)d_in[13];
    float* out = (float*)d_out;
    (void)ws_size; (void)n_in; (void)out_size;

    const int N = in_sizes[0] / 256;   // 40000
    const int E = in_sizes[2];         // 500000
    const int* srcp = ei;
    const int* dstp = ei + E;

    // ---- workspace map (peak 251,360,256 bytes) ----
    char* ws = (char*)d_ws;
    int*   cnt   = (int*)ws;                                   // 480,256 B
    float* h1    = (float*)(ws + 480256);                      // N*1024*4 = 163,840,000
    float* regB  = (float*)(ws + 480256 + 163840000);          // 81,920,000
    __hip_bfloat16* chunk = (__hip_bfloat16*)(ws + 480256 + 163840000 + 81920000); // 5,120,000
    float* Abuf = regB;                         // layer-1 aggregate (N*256)
    float* h2   = regB;                         // layer-2 output (N*512)
    float* H3   = h1;                           // layer-3 per-rel H (N*128), h1 dead
    float* h3   = (float*)((char*)h1 + 33554432); // N*128*4 = 20,480,000, inside region A

    // ---- degree counts per (dst, rel) ----
    zero_kernel<<<(N * 3 / 4 + 255) / 256, 256, 0, stream>>>((float*)cnt, (long)N * 3 / 4);
    count_kernel<<<(E + 255) / 256, 256, 0, stream>>>(dstp, etp, cnt, E);

    // ---- layer 1 (aggregate-first, per relation) ----
    // h1 = x @ root1 + b1
    gemm64<<<dim3(16, N / 64), 256, 0, stream>>>(x, root1, b1, h1, N, 1024, 256, 1024, 0);
    for (int r = 0; r < 3; ++r) {
        zero_kernel<<<((long)N * 256 / 4 + 255) / 256, 256, 0, stream>>>(Abuf, (long)N * 256 / 4);
        scatter1_kernel<<<(int)(((long)E * 64) / 256), 256, 0, stream>>>(
            x, srcp, dstp, etp, cnt, Abuf, E, r);
        gemm64<<<dim3(16, N / 64), 256, 0, stream>>>(
            Abuf, W1 + (size_t)r * 256 * 1024, nullptr, h1, N, 1024, 256, 1024,
            FLAG_ACC | (r == 2 ? FLAG_RELU : 0));
    }

    // ---- layer 2 (transform-first, per relation, 64-col bf16 chunks) ----
    gemm64<<<dim3(8, N / 64), 256, 0, stream>>>(h1, root2, b2, h2, N, 512, 1024, 512, 0);
    for (int r = 0; r < 3; ++r) {
        for (int c0 = 0; c0 < 512; c0 += 64) {
            gemm64<<<dim3(1, N / 64), 256, 0, stream>>>(
                h1, W2 + (size_t)r * 1024 * 512 + c0, nullptr, chunk, N, 64, 1024, 512, FLAG_BF16);
            scatter2_kernel<<<(int)(((long)E * 16) / 256), 256, 0, stream>>>(
                chunk, srcp, dstp, etp, cnt, h2, E, r, c0);
        }
    }
    relu_kernel<<<(int)(((long)N * 512 / 4 + 255) / 256), 256, 0, stream>>>(h2, (long)N * 512 / 4);

    // ---- layer 3 (transform-first, per relation, full 128-col f32 H) ----
    gemm64<<<dim3(2, N / 64), 256, 0, stream>>>(h2, root3, b3, h3, N, 128, 512, 128, 0);
    for (int r = 0; r < 3; ++r) {
        gemm64<<<dim3(2, N / 64), 256, 0, stream>>>(
            h2, W3 + (size_t)r * 512 * 128, nullptr, H3, N, 128, 512, 128, 0);
        scatter3_kernel<<<(int)(((long)E * 32) / 256), 256, 0, stream>>>(
            H3, srcp, dstp, etp, cnt, h3, E, r);
    }

    // ---- FC head + log_softmax (relu of h3 fused into load) ----
    head_kernel<<<N / 4, 256, 0, stream>>>(h3, fcw, fcb, out, N);
}

// Round 3
// 6498.634 us; speedup vs baseline: 1.6273x; 1.6273x over previous
//
#include <hip/hip_runtime.h>
#include <cstdint>
#include <cstddef>

// ---------------------------------------------------------------------------
// RGCN 3-layer + FC head. GEMMs in bf16 MFMA (16x16x32), scatters in f32
// atomics. Weights pre-transposed to [Nout][K] bf16 so A and B staging are
// identical ([spatial][k] LDS tiles, XOR-swizzled, global_load_lds x16).
// Workspace peak ~212 MB (< 251 MB proven in round 2).
// ---------------------------------------------------------------------------

typedef short bf16x8 __attribute__((ext_vector_type(8)));
typedef float f32x4 __attribute__((ext_vector_type(4)));

#define GF_BIAS 1
#define GF_RELU 2
#define GF_BF16 4

__device__ __forceinline__ unsigned short f2bf(float f) {
    unsigned u = __float_as_uint(f);
    return (unsigned short)((u + 0x7FFFu + ((u >> 16) & 1u)) >> 16);
}
__device__ __forceinline__ float bf2f(unsigned short h) {
    return __uint_as_float((unsigned)h << 16);
}

__global__ __launch_bounds__(256) void zero_kernel(float* __restrict__ p, long n4)
{
    long i = (long)blockIdx.x * 256 + threadIdx.x;
    if (i < n4) ((float4*)p)[i] = make_float4(0.f, 0.f, 0.f, 0.f);
}

__global__ __launch_bounds__(256) void count_kernel(
    const int* __restrict__ dst, const int* __restrict__ et,
    int* __restrict__ cnt, int E)
{
    int e = blockIdx.x * 256 + threadIdx.x;
    if (e < E) atomicAdd(&cnt[dst[e] * 3 + et[e]], 1);
}

// transpose + f32->bf16: out[j*ldo + i] = bf16(in[i*C + j]), i<R, j<C
__global__ __launch_bounds__(256) void transpose_bf16(
    const float* __restrict__ in, unsigned short* __restrict__ out,
    int R, int C, int ldo)
{
    int idx = blockIdx.x * 256 + threadIdx.x;
    if (idx >= R * C) return;
    int j = idx / R, i = idx - j * R;
    out[(size_t)j * ldo + i] = f2bf(in[(size_t)i * C + j]);
}

// f32 [row][sld] (cols at 0) -> bf16 dst[row][dld] at column offset coff.
// One thread = 8 elements. total = rows * cols8.
__global__ __launch_bounds__(256) void pack_bf16(
    const float* __restrict__ src, unsigned short* __restrict__ dst,
    long total, int cols8, int sld, int dld, int coff, int relu)
{
    long idx = (long)blockIdx.x * 256 + threadIdx.x;
    if (idx >= total) return;
    int c8 = (int)(idx % cols8);
    long row = idx / cols8;
    const float* s = src + row * sld + (size_t)c8 * 8;
    float4 v0 = *(const float4*)s;
    float4 v1 = *(const float4*)(s + 4);
    if (relu) {
        v0.x = fmaxf(v0.x, 0.f); v0.y = fmaxf(v0.y, 0.f);
        v0.z = fmaxf(v0.z, 0.f); v0.w = fmaxf(v0.w, 0.f);
        v1.x = fmaxf(v1.x, 0.f); v1.y = fmaxf(v1.y, 0.f);
        v1.z = fmaxf(v1.z, 0.f); v1.w = fmaxf(v1.w, 0.f);
    }
    unsigned short* d = dst + row * dld + coff + (size_t)c8 * 8;
    ushort4 o0, o1;
    o0.x = f2bf(v0.x); o0.y = f2bf(v0.y); o0.z = f2bf(v0.z); o0.w = f2bf(v0.w);
    o1.x = f2bf(v1.x); o1.y = f2bf(v1.y); o1.z = f2bf(v1.z); o1.w = f2bf(v1.w);
    *(ushort4*)d = o0;
    *(ushort4*)(d + 4) = o1;
}

// Layer-1 scatter (single pass): A[dst, et*256 + c] += x[src, c] * norm
__global__ __launch_bounds__(256) void scatter1_all(
    const float* __restrict__ x, const int* __restrict__ src,
    const int* __restrict__ dst, const int* __restrict__ et,
    const int* __restrict__ cnt, float* __restrict__ A, int E)
{
    long tid = (long)blockIdx.x * 256 + threadIdx.x;
    int e = (int)(tid >> 6);
    if (e >= E) return;
    int c = (int)(tid & 63);
    int s = src[e], d = dst[e], r = et[e];
    int cv = cnt[d * 3 + r];
    float norm = 1.0f / (float)(cv > 0 ? cv : 1);
    float4 v = *(const float4*)&x[(size_t)s * 256 + c * 4];
    float* o = &A[(size_t)d * 768 + r * 256 + c * 4];
    atomicAdd(o + 0, v.x * norm);
    atomicAdd(o + 1, v.y * norm);
    atomicAdd(o + 2, v.z * norm);
    atomicAdd(o + 3, v.w * norm);
}

// Layer-2 scatter (relation r): h2[dst, c] += f32(H[src, c]) * norm, 512 cols
__global__ __launch_bounds__(256) void scatter2_kernel(
    const unsigned short* __restrict__ H, const int* __restrict__ src,
    const int* __restrict__ dst, const int* __restrict__ et,
    const int* __restrict__ cnt, float* __restrict__ h2, int E, int r)
{
    long tid = (long)blockIdx.x * 256 + threadIdx.x;
    int e = (int)(tid >> 7);
    if (e >= E) return;
    if (et[e] != r) return;
    int c = (int)(tid & 127);
    int s = src[e], d = dst[e];
    int cv = cnt[d * 3 + r];
    float norm = 1.0f / (float)(cv > 0 ? cv : 1);
    ushort4 raw = *(const ushort4*)&H[(size_t)s * 512 + c * 4];
    float* o = &h2[(size_t)d * 512 + c * 4];
    atomicAdd(o + 0, bf2f(raw.x) * norm);
    atomicAdd(o + 1, bf2f(raw.y) * norm);
    atomicAdd(o + 2, bf2f(raw.z) * norm);
    atomicAdd(o + 3, bf2f(raw.w) * norm);
}

// Layer-3 scatter (single pass): h3[dst, c] += f32(H3[src, et*128 + c]) * norm
__global__ __launch_bounds__(256) void scatter3_all(
    const unsigned short* __restrict__ H3, const int* __restrict__ src,
    const int* __restrict__ dst, const int* __restrict__ et,
    const int* __restrict__ cnt, float* __restrict__ h3, int E)
{
    long tid = (long)blockIdx.x * 256 + threadIdx.x;
    int e = (int)(tid >> 5);
    if (e >= E) return;
    int c = (int)(tid & 31);
    int s = src[e], d = dst[e], r = et[e];
    int cv = cnt[d * 3 + r];
    float norm = 1.0f / (float)(cv > 0 ? cv : 1);
    ushort4 raw = *(const ushort4*)&H3[(size_t)s * 384 + r * 128 + c * 4];
    float* o = &h3[(size_t)d * 128 + c * 4];
    atomicAdd(o + 0, bf2f(raw.x) * norm);
    atomicAdd(o + 1, bf2f(raw.y) * norm);
    atomicAdd(o + 2, bf2f(raw.z) * norm);
    atomicAdd(o + 3, bf2f(raw.w) * norm);
}

// ---------------------------------------------------------------------------
// MFMA GEMM: C[M,Nout] = A[M,K](bf16) @ Bt[Nout,K](bf16)^T  (+bias)(+relu)
// 128x128 tile, BK=64, 4 waves (2x2), each wave 64x64 via 4x4 16x16 frags.
// LDS [128 rows][64 k] bf16, XOR swizzle col8 ^= (row&7); staged with
// global_load_lds x16 (linear dest, pre-swizzled global source).
// Grid: (Nout/128, Mpad/128). All rows < Mpad must be readable/writable.
// ---------------------------------------------------------------------------
__global__ __launch_bounds__(256) void gemm_mfma(
    const unsigned short* __restrict__ A, const unsigned short* __restrict__ Bt,
    const float* __restrict__ bias, void* __restrict__ C,
    int Nout, int K, int ldbt, int flags)
{
    __shared__ short __align__(16) As[8192];   // 16 KB
    __shared__ short __align__(16) Bs[8192];
    const int tid = threadIdx.x;
    const int w = tid >> 6, l = tid & 63;
    const int row0 = blockIdx.y * 128, col0 = blockIdx.x * 128;
    const int wm = w >> 1, wn = w & 1;
    const int lr = l >> 3;   // row within 8-row chunk
    const int lc = l & 7;    // col8 pre-swizzle

    f32x4 acc[4][4];
#pragma unroll
    for (int i = 0; i < 4; ++i)
#pragma unroll
        for (int j = 0; j < 4; ++j) acc[i][j] = (f32x4){0.f, 0.f, 0.f, 0.f};

    for (int k0 = 0; k0 < K; k0 += 64) {
        __syncthreads();   // all waves done reading previous tile
#pragma unroll
        for (int i = 0; i < 4; ++i) {
            const int c  = i * 4 + w;            // chunk 0..15 (1 KB each)
            const int r  = c * 8 + lr;           // tile row 0..127
            const int c8 = lc ^ (r & 7);         // swizzled k-octet
            __builtin_amdgcn_global_load_lds(
                (const __attribute__((address_space(1))) void*)
                    (A + (size_t)(row0 + r) * K + k0 + c8 * 8),
                (__attribute__((address_space(3))) void*)(As + c * 512),
                16, 0, 0);
            __builtin_amdgcn_global_load_lds(
                (const __attribute__((address_space(1))) void*)
                    (Bt + (size_t)(col0 + r) * ldbt + k0 + c8 * 8),
                (__attribute__((address_space(3))) void*)(Bs + c * 512),
                16, 0, 0);
        }
        __syncthreads();   // loads complete (vmcnt drained at barrier)
#pragma unroll
        for (int ks = 0; ks < 2; ++ks) {
            bf16x8 af[4], bf[4];
#pragma unroll
            for (int mf = 0; mf < 4; ++mf) {
                int r = wm * 64 + mf * 16 + (l & 15);
                int byt = (r * 128 + ks * 64 + (l >> 4) * 16) ^ ((r & 7) << 4);
                af[mf] = *(const bf16x8*)((const char*)As + byt);
            }
#pragma unroll
            for (int nf = 0; nf < 4; ++nf) {
                int r = wn * 64 + nf * 16 + (l & 15);
                int byt = (r * 128 + ks * 64 + (l >> 4) * 16) ^ ((r & 7) << 4);
                bf[nf] = *(const bf16x8*)((const char*)Bs + byt);
            }
#pragma unroll
            for (int mf = 0; mf < 4; ++mf)
#pragma unroll
                for (int nf = 0; nf < 4; ++nf)
                    acc[mf][nf] = __builtin_amdgcn_mfma_f32_16x16x32_bf16(
                        af[mf], bf[nf], acc[mf][nf], 0, 0, 0);
        }
    }

    const int lrow = (l >> 4) * 4;
    const int lcol = l & 15;
#pragma unroll
    for (int mf = 0; mf < 4; ++mf) {
#pragma unroll
        for (int nf = 0; nf < 4; ++nf) {
            int col = col0 + wn * 64 + nf * 16 + lcol;
            float bv = (flags & GF_BIAS) ? bias[col] : 0.f;
#pragma unroll
            for (int rr = 0; rr < 4; ++rr) {
                int row = row0 + wm * 64 + mf * 16 + lrow + rr;
                float v = acc[mf][nf][rr] + bv;
                if (flags & GF_RELU) v = fmaxf(v, 0.f);
                size_t idx = (size_t)row * Nout + col;
                if (flags & GF_BF16) ((unsigned short*)C)[idx] = f2bf(v);
                else                 ((float*)C)[idx] = v;
            }
        }
    }
}

// logits = relu(h3) @ fcw + fcb; out = log_softmax. One wave per row.
__global__ __launch_bounds__(256) void head_kernel(
    const float* __restrict__ h3, const float* __restrict__ fcw,
    const float* __restrict__ fcb, float* __restrict__ out, int M)
{
    __shared__ float sh[4][128];
    int wid = threadIdx.x >> 6, lane = threadIdx.x & 63;
    int row = blockIdx.x * 4 + wid;
    sh[wid][lane]      = fmaxf(h3[(size_t)row * 128 + lane], 0.f);
    sh[wid][64 + lane] = fmaxf(h3[(size_t)row * 128 + 64 + lane], 0.f);
    __syncthreads();
    float logit = 0.f;
    if (lane < 21) {
        logit = fcb[lane];
#pragma unroll
        for (int k = 0; k < 128; ++k) logit += sh[wid][k] * fcw[k * 21 + lane];
    }
    float v = (lane < 21) ? logit : -INFINITY;
#pragma unroll
    for (int off = 32; off; off >>= 1) v = fmaxf(v, __shfl_xor(v, off));
    float mx = v;
    float ex = (lane < 21) ? expf(logit - mx) : 0.f;
#pragma unroll
    for (int off = 32; off; off >>= 1) ex += __shfl_xor(ex, off);
    if (lane < 21) out[(size_t)row * 21 + lane] = logit - mx - logf(ex);
}

extern "C" void kernel_launch(void* const* d_in, const int* in_sizes, int n_in,
                              void* d_out, int out_size, void* d_ws, size_t ws_size,
                              hipStream_t stream)
{
    const float* x     = (const float*)d_in[0];
    const int*   ei    = (const int*)d_in[1];
    const int*   etp   = (const int*)d_in[2];
    const float* W1    = (const float*)d_in[3];
    const float* root1 = (const float*)d_in[4];
    const float* b1    = (const float*)d_in[5];
    const float* W2    = (const float*)d_in[6];
    const float* root2 = (const float*)d_in[7];
    const float* b2    = (const float*)d_in[8];
    const float* W3    = (const float*)d_in[9];
    const float* root3 = (const float*)d_in[10];
    const float* b3    = (const float*)d_in[11];
    const float* fcw   = (const float*)d_in[12];
    const float* fcb   = (const float*)d_in[13];
    float* out = (float*)d_out;
    (void)ws_size; (void)n_in; (void)out_size;

    const int N  = in_sizes[0] / 256;            // 40000
    const int E  = in_sizes[2];                  // 500000
    const int NP = (N + 127) / 128 * 128;        // 40064 (padded rows)
    const int GY = NP / 128;                     // 313
    const int* srcp = ei;
    const int* dstp = ei + E;

    // ---- workspace map (~212.4 MB peak) ----
    char* ws = (char*)d_ws;
    int*            cnt  = (int*)ws;                              //   480,256 B
    unsigned short* W1t  = (unsigned short*)(ws + 480256);        // 1024x1024 bf16
    unsigned short* W2t  = (unsigned short*)(ws + 2577408);       // 512x3072
    unsigned short* r2t  = (unsigned short*)(ws + 5723136);       // 512x1024
    unsigned short* W3t  = (unsigned short*)(ws + 6771712);       // 384x512
    unsigned short* r3t  = (unsigned short*)(ws + 7164928);       // 128x512
    char* arena = ws + 7296256;
    unsigned short* Xcat = (unsigned short*)(arena);              // NP x 1024 bf16
    float*          Aall = (float*)(arena + 82051072);            // N  x 768  f32
    unsigned short* h1b  = (unsigned short*)(arena + 82051072);   // NP x 1024 bf16 (Aall dead)
    float*          h2   = (float*)(arena);                       // NP x 512  f32 (Xcat dead)
    unsigned short* H2q  = (unsigned short*)(arena + 164102144);  // NP x 512  bf16
    unsigned short* h2b  = (unsigned short*)(arena + 164102144);  // NP x 512  bf16 (H2q dead)
    unsigned short* H3   = (unsigned short*)(arena);              // NP x 384  bf16 (h2 dead)
    float*          h3   = (float*)(arena + 30769152);            // NP x 128  f32

    // ---- degree counts per (dst, rel) ----
    zero_kernel<<<(N * 3 / 4 + 255) / 256, 256, 0, stream>>>((float*)cnt, (long)N * 3 / 4);
    count_kernel<<<(E + 255) / 256, 256, 0, stream>>>(dstp, etp, cnt, E);

    // ---- weight transposes (f32 -> bf16, [Nout][K]) ----
    transpose_bf16<<<(768 * 1024 + 255) / 256, 256, 0, stream>>>(W1, W1t, 768, 1024, 1024);
    transpose_bf16<<<(256 * 1024 + 255) / 256, 256, 0, stream>>>(root1, W1t + 768, 256, 1024, 1024);
    transpose_bf16<<<(3072 * 512 + 255) / 256, 256, 0, stream>>>(W2, W2t, 3072, 512, 3072);
    transpose_bf16<<<(1024 * 512 + 255) / 256, 256, 0, stream>>>(root2, r2t, 1024, 512, 1024);
    for (int r = 0; r < 3; ++r)
        transpose_bf16<<<(512 * 128 + 255) / 256, 256, 0, stream>>>(
            W3 + (size_t)r * 65536, W3t + (size_t)r * 65536, 512, 128, 512);
    transpose_bf16<<<(512 * 128 + 255) / 256, 256, 0, stream>>>(root3, r3t, 512, 128, 512);

    // ---- layer 1: aggregate-first, single scatter pass, one GEMM ----
    zero_kernel<<<((long)N * 768 / 4 + 255) / 256, 256, 0, stream>>>(Aall, (long)N * 768 / 4);
    scatter1_all<<<(int)(((long)E * 64 + 255) / 256), 256, 0, stream>>>(
        x, srcp, dstp, etp, cnt, Aall, E);
    pack_bf16<<<(int)(((long)N * 96 + 255) / 256), 256, 0, stream>>>(
        Aall, Xcat, (long)N * 96, 96, 768, 1024, 0, 0);
    pack_bf16<<<(int)(((long)N * 32 + 255) / 256), 256, 0, stream>>>(
        x, Xcat, (long)N * 32, 32, 256, 1024, 768, 0);
    gemm_mfma<<<dim3(8, GY), 256, 0, stream>>>(
        Xcat, W1t, b1, h1b, 1024, 1024, 1024, GF_BIAS | GF_RELU | GF_BF16);

    // ---- layer 2: root GEMM (f32 + bias), then per-relation H + scatter ----
    gemm_mfma<<<dim3(4, GY), 256, 0, stream>>>(
        h1b, r2t, b2, h2, 512, 1024, 1024, GF_BIAS);
    for (int r = 0; r < 3; ++r) {
        gemm_mfma<<<dim3(4, GY), 256, 0, stream>>>(
            h1b, W2t + (size_t)r * 1024, nullptr, H2q, 512, 1024, 3072, GF_BF16);
        scatter2_kernel<<<(int)(((long)E * 128 + 255) / 256), 256, 0, stream>>>(
            H2q, srcp, dstp, etp, cnt, h2, E, r);
    }
    pack_bf16<<<(int)(((long)N * 64 + 255) / 256), 256, 0, stream>>>(
        h2, h2b, (long)N * 64, 64, 512, 512, 0, 1);   // relu fused

    // ---- layer 3: one GEMM (N=384) + root GEMM + single scatter pass ----
    gemm_mfma<<<dim3(3, GY), 256, 0, stream>>>(
        h2b, W3t, nullptr, H3, 384, 512, 512, GF_BF16);
    gemm_mfma<<<dim3(1, GY), 256, 0, stream>>>(
        h2b, r3t, b3, h3, 128, 512, 512, GF_BIAS);
    scatter3_all<<<(int)(((long)E * 32 + 255) / 256), 256, 0, stream>>>(
        H3, srcp, dstp, etp, cnt, h3, E);

    // ---- FC head + log_softmax (relu fused into load) ----
    head_kernel<<<N / 4, 256, 0, stream>>>(h3, fcw, fcb, out, N);
}

// Round 4
// 856.859 us; speedup vs baseline: 12.3421x; 7.5843x over previous
//
#include <hip/hip_runtime.h>
#include <cstdint>
#include <cstddef>

// ---------------------------------------------------------------------------
// RGCN 3-layer + FC head. bf16 MFMA GEMMs + CSR gather-based aggregation
// (zero atomics in the hot path). CSR built per call: count -> scan -> fill.
// Workspace peak ~215.4 MB (< 251.4 MB proven).
// ---------------------------------------------------------------------------

typedef short bf16x8 __attribute__((ext_vector_type(8)));
typedef float f32x4 __attribute__((ext_vector_type(4)));

#define GF_BIAS 1
#define GF_RELU 2
#define GF_BF16 4

__device__ __forceinline__ unsigned short f2bf(float f) {
    unsigned u = __float_as_uint(f);
    return (unsigned short)((u + 0x7FFFu + ((u >> 16) & 1u)) >> 16);
}
__device__ __forceinline__ float bf2f(unsigned short h) {
    return __uint_as_float((unsigned)h << 16);
}

__global__ __launch_bounds__(256) void zero_kernel(float* __restrict__ p, long n4)
{
    long i = (long)blockIdx.x * 256 + threadIdx.x;
    if (i < n4) ((float4*)p)[i] = make_float4(0.f, 0.f, 0.f, 0.f);
}

__global__ __launch_bounds__(256) void count_kernel(
    const int* __restrict__ dst, const int* __restrict__ et,
    int* __restrict__ cnt, int E)
{
    int e = blockIdx.x * 256 + threadIdx.x;
    if (e < E) atomicAdd(&cnt[dst[e] * 3 + et[e]], 1);
}

// ---- 2-level exclusive scan over S ints ----
__global__ __launch_bounds__(256) void scanA(
    const int* __restrict__ cnt, int* __restrict__ base,
    int* __restrict__ bsum, int S)
{
    __shared__ int sh[256];
    int i = blockIdx.x * 256 + threadIdx.x;
    int v = (i < S) ? cnt[i] : 0;
    sh[threadIdx.x] = v;
    __syncthreads();
#pragma unroll
    for (int off = 1; off < 256; off <<= 1) {
        int t = (threadIdx.x >= off) ? sh[threadIdx.x - off] : 0;
        __syncthreads();
        sh[threadIdx.x] += t;
        __syncthreads();
    }
    if (i < S) base[i] = sh[threadIdx.x] - v;           // exclusive
    if (threadIdx.x == 255) bsum[blockIdx.x] = sh[255]; // block total
}

__global__ __launch_bounds__(512) void scanB(int* __restrict__ bsum, int NB)
{
    __shared__ int sh[512];
    int t = threadIdx.x;
    int v = (t < NB) ? bsum[t] : 0;
    sh[t] = v;
    __syncthreads();
#pragma unroll
    for (int off = 1; off < 512; off <<= 1) {
        int u = (t >= off) ? sh[t - off] : 0;
        __syncthreads();
        sh[t] += u;
        __syncthreads();
    }
    if (t < NB) bsum[t] = sh[t] - v;                    // exclusive
}

__global__ __launch_bounds__(256) void scanC(
    int* __restrict__ base, const int* __restrict__ bsum, int S)
{
    int i = blockIdx.x * 256 + threadIdx.x;
    if (i < S) base[i] += bsum[blockIdx.x];
}

__global__ __launch_bounds__(256) void fill_kernel(
    const int* __restrict__ src, const int* __restrict__ dst,
    const int* __restrict__ et, const int* __restrict__ base,
    int* __restrict__ ecur, int* __restrict__ elist, int E)
{
    int e = blockIdx.x * 256 + threadIdx.x;
    if (e >= E) return;
    int seg = dst[e] * 3 + et[e];
    int pos = base[seg] + atomicAdd(&ecur[seg], 1);
    elist[pos] = src[e];
}

// transpose + f32->bf16: out[j*ldo + i] = bf16(in[i*C + j]), i<R, j<C
__global__ __launch_bounds__(256) void transpose_bf16(
    const float* __restrict__ in, unsigned short* __restrict__ out,
    int R, int C, int ldo)
{
    int idx = blockIdx.x * 256 + threadIdx.x;
    if (idx >= R * C) return;
    int j = idx / R, i = idx - j * R;
    out[(size_t)j * ldo + i] = f2bf(in[(size_t)i * C + j]);
}

// Layer-1 aggregate (gather): block = 4 waves, one node row n each.
// Wave r<3: Xcat[n, r*256+c] = bf16( mean over seg(n,r) of x[src, c] )
// Wave 3:   Xcat[n, 768+c]   = bf16( x[n, c] )
__global__ __launch_bounds__(256) void agg1_kernel(
    const float* __restrict__ x, const int* __restrict__ base,
    const int* __restrict__ cnt, const int* __restrict__ elist,
    unsigned short* __restrict__ Xcat, int N)
{
    int n = blockIdx.x;
    int w = threadIdx.x >> 6, l = threadIdx.x & 63;
    if (w == 3) {
        float4 v = *(const float4*)&x[(size_t)n * 256 + l * 4];
        ushort4 o; o.x = f2bf(v.x); o.y = f2bf(v.y); o.z = f2bf(v.z); o.w = f2bf(v.w);
        *(ushort4*)&Xcat[(size_t)n * 1024 + 768 + l * 4] = o;
        return;
    }
    int seg = n * 3 + w;
    int st = base[seg], len = cnt[seg];
    float norm = 1.0f / (float)(len > 0 ? len : 1);
    float4 s = make_float4(0.f, 0.f, 0.f, 0.f);
    for (int i = 0; i < len; ++i) {
        int sidx = elist[st + i];
        float4 v = *(const float4*)&x[(size_t)sidx * 256 + l * 4];
        s.x += v.x; s.y += v.y; s.z += v.z; s.w += v.w;
    }
    ushort4 o;
    o.x = f2bf(s.x * norm); o.y = f2bf(s.y * norm);
    o.z = f2bf(s.z * norm); o.w = f2bf(s.w * norm);
    *(ushort4*)&Xcat[(size_t)n * 1024 + w * 256 + l * 4] = o;
}

// Layer-2 aggregate (gather, relation r): block = 128 threads, node n.
// acc = h2acc[n, c] + mean over seg(n,r) of bf16 H2q[src, c]
// r<2: h2acc = acc ; r==2: h2b[n,c] = bf16(relu(acc))
__global__ __launch_bounds__(128) void agg2_kernel(
    const unsigned short* __restrict__ H2q, float* __restrict__ h2acc,
    unsigned short* __restrict__ h2b, const int* __restrict__ base,
    const int* __restrict__ cnt, const int* __restrict__ elist, int r, int last)
{
    int n = blockIdx.x;
    int t = threadIdx.x;                 // owns cols t*4 .. t*4+3
    int seg = n * 3 + r;
    int st = base[seg], len = cnt[seg];
    float norm = 1.0f / (float)(len > 0 ? len : 1);
    float4 s = make_float4(0.f, 0.f, 0.f, 0.f);
    for (int i = 0; i < len; ++i) {
        int sidx = elist[st + i];
        ushort4 v = *(const ushort4*)&H2q[(size_t)sidx * 512 + t * 4];
        s.x += bf2f(v.x); s.y += bf2f(v.y); s.z += bf2f(v.z); s.w += bf2f(v.w);
    }
    float4 a = *(const float4*)&h2acc[(size_t)n * 512 + t * 4];
    a.x += s.x * norm; a.y += s.y * norm; a.z += s.z * norm; a.w += s.w * norm;
    if (!last) {
        *(float4*)&h2acc[(size_t)n * 512 + t * 4] = a;
    } else {
        ushort4 o;
        o.x = f2bf(fmaxf(a.x, 0.f)); o.y = f2bf(fmaxf(a.y, 0.f));
        o.z = f2bf(fmaxf(a.z, 0.f)); o.w = f2bf(fmaxf(a.w, 0.f));
        *(ushort4*)&h2b[(size_t)n * 512 + t * 4] = o;
    }
}

// Layer-3 aggregate (gather, all relations): 1 wave per node, lane owns 2 cols.
// h3[n,c] = h3root[n,c] + sum_r mean over seg(n,r) of H3all[src, r*128+c]
__global__ __launch_bounds__(64) void agg3_kernel(
    const unsigned short* __restrict__ H3all, const float* __restrict__ h3root,
    float* __restrict__ h3, const int* __restrict__ base,
    const int* __restrict__ cnt, const int* __restrict__ elist)
{
    int n = blockIdx.x;
    int l = threadIdx.x;                 // owns cols l*2, l*2+1
    float s0 = 0.f, s1 = 0.f;
#pragma unroll
    for (int r = 0; r < 3; ++r) {
        int seg = n * 3 + r;
        int st = base[seg], len = cnt[seg];
        float norm = 1.0f / (float)(len > 0 ? len : 1);
        float t0 = 0.f, t1 = 0.f;
        for (int i = 0; i < len; ++i) {
            int sidx = elist[st + i];
            ushort2 v = *(const ushort2*)&H3all[(size_t)sidx * 384 + r * 128 + l * 2];
            t0 += bf2f(v.x); t1 += bf2f(v.y);
        }
        s0 += t0 * norm; s1 += t1 * norm;
    }
    float2 rt = *(const float2*)&h3root[(size_t)n * 128 + l * 2];
    float2 o; o.x = rt.x + s0; o.y = rt.y + s1;
    *(float2*)&h3[(size_t)n * 128 + l * 2] = o;
}

// ---------------------------------------------------------------------------
// MFMA GEMM: C[M,Nout] = A[M,K](bf16) @ Bt[Nout,K](bf16)^T  (+bias)(+relu)
// 128x128 tile, BK=64, 4 waves, XOR-swizzled LDS, global_load_lds x16.
// ---------------------------------------------------------------------------
__global__ __launch_bounds__(256) void gemm_mfma(
    const unsigned short* __restrict__ A, const unsigned short* __restrict__ Bt,
    const float* __restrict__ bias, void* __restrict__ C,
    int Nout, int K, int ldbt, int flags)
{
    __shared__ short __align__(16) As[8192];
    __shared__ short __align__(16) Bs[8192];
    const int tid = threadIdx.x;
    const int w = tid >> 6, l = tid & 63;
    const int row0 = blockIdx.y * 128, col0 = blockIdx.x * 128;
    const int wm = w >> 1, wn = w & 1;
    const int lr = l >> 3, lc = l & 7;

    f32x4 acc[4][4];
#pragma unroll
    for (int i = 0; i < 4; ++i)
#pragma unroll
        for (int j = 0; j < 4; ++j) acc[i][j] = (f32x4){0.f, 0.f, 0.f, 0.f};

    for (int k0 = 0; k0 < K; k0 += 64) {
        __syncthreads();
#pragma unroll
        for (int i = 0; i < 4; ++i) {
            const int c  = i * 4 + w;
            const int r  = c * 8 + lr;
            const int c8 = lc ^ (r & 7);
            __builtin_amdgcn_global_load_lds(
                (const __attribute__((address_space(1))) void*)
                    (A + (size_t)(row0 + r) * K + k0 + c8 * 8),
                (__attribute__((address_space(3))) void*)(As + c * 512),
                16, 0, 0);
            __builtin_amdgcn_global_load_lds(
                (const __attribute__((address_space(1))) void*)
                    (Bt + (size_t)(col0 + r) * ldbt + k0 + c8 * 8),
                (__attribute__((address_space(3))) void*)(Bs + c * 512),
                16, 0, 0);
        }
        __syncthreads();
#pragma unroll
        for (int ks = 0; ks < 2; ++ks) {
            bf16x8 af[4], bfv[4];
#pragma unroll
            for (int mf = 0; mf < 4; ++mf) {
                int r = wm * 64 + mf * 16 + (l & 15);
                int byt = (r * 128 + ks * 64 + (l >> 4) * 16) ^ ((r & 7) << 4);
                af[mf] = *(const bf16x8*)((const char*)As + byt);
            }
#pragma unroll
            for (int nf = 0; nf < 4; ++nf) {
                int r = wn * 64 + nf * 16 + (l & 15);
                int byt = (r * 128 + ks * 64 + (l >> 4) * 16) ^ ((r & 7) << 4);
                bfv[nf] = *(const bf16x8*)((const char*)Bs + byt);
            }
#pragma unroll
            for (int mf = 0; mf < 4; ++mf)
#pragma unroll
                for (int nf = 0; nf < 4; ++nf)
                    acc[mf][nf] = __builtin_amdgcn_mfma_f32_16x16x32_bf16(
                        af[mf], bfv[nf], acc[mf][nf], 0, 0, 0);
        }
    }

    const int lrow = (l >> 4) * 4;
    const int lcol = l & 15;
#pragma unroll
    for (int mf = 0; mf < 4; ++mf) {
#pragma unroll
        for (int nf = 0; nf < 4; ++nf) {
            int col = col0 + wn * 64 + nf * 16 + lcol;
            float bv = (flags & GF_BIAS) ? bias[col] : 0.f;
#pragma unroll
            for (int rr = 0; rr < 4; ++rr) {
                int row = row0 + wm * 64 + mf * 16 + lrow + rr;
                float v = acc[mf][nf][rr] + bv;
                if (flags & GF_RELU) v = fmaxf(v, 0.f);
                size_t idx = (size_t)row * Nout + col;
                if (flags & GF_BF16) ((unsigned short*)C)[idx] = f2bf(v);
                else                 ((float*)C)[idx] = v;
            }
        }
    }
}

// logits = relu(h3) @ fcw + fcb; out = log_softmax. One wave per row.
__global__ __launch_bounds__(256) void head_kernel(
    const float* __restrict__ h3, const float* __restrict__ fcw,
    const float* __restrict__ fcb, float* __restrict__ out, int M)
{
    __shared__ float sh[4][128];
    int wid = threadIdx.x >> 6, lane = threadIdx.x & 63;
    int row = blockIdx.x * 4 + wid;
    sh[wid][lane]      = fmaxf(h3[(size_t)row * 128 + lane], 0.f);
    sh[wid][64 + lane] = fmaxf(h3[(size_t)row * 128 + 64 + lane], 0.f);
    __syncthreads();
    float logit = 0.f;
    if (lane < 21) {
        logit = fcb[lane];
#pragma unroll
        for (int k = 0; k < 128; ++k) logit += sh[wid][k] * fcw[k * 21 + lane];
    }
    float v = (lane < 21) ? logit : -INFINITY;
#pragma unroll
    for (int off = 32; off; off >>= 1) v = fmaxf(v, __shfl_xor(v, off));
    float mx = v;
    float ex = (lane < 21) ? expf(logit - mx) : 0.f;
#pragma unroll
    for (int off = 32; off; off >>= 1) ex += __shfl_xor(ex, off);
    if (lane < 21) out[(size_t)row * 21 + lane] = logit - mx - logf(ex);
}

extern "C" void kernel_launch(void* const* d_in, const int* in_sizes, int n_in,
                              void* d_out, int out_size, void* d_ws, size_t ws_size,
                              hipStream_t stream)
{
    const float* x     = (const float*)d_in[0];
    const int*   ei    = (const int*)d_in[1];
    const int*   etp   = (const int*)d_in[2];
    const float* W1    = (const float*)d_in[3];
    const float* root1 = (const float*)d_in[4];
    const float* b1    = (const float*)d_in[5];
    const float* W2    = (const float*)d_in[6];
    const float* root2 = (const float*)d_in[7];
    const float* b2    = (const float*)d_in[8];
    const float* W3    = (const float*)d_in[9];
    const float* root3 = (const float*)d_in[10];
    const float* b3    = (const float*)d_in[11];
    const float* fcw   = (const float*)d_in[12];
    const float* fcb   = (const float*)d_in[13];
    float* out = (float*)d_out;
    (void)ws_size; (void)n_in; (void)out_size;

    const int N  = in_sizes[0] / 256;            // 40000
    const int E  = in_sizes[2];                  // 500000
    const int S  = N * 3;                        // 120000 segments
    const int NP = (N + 127) / 128 * 128;        // 40064
    const int GY = NP / 128;                     // 313
    const int NB = (S + 255) / 256;              // 469 scan blocks
    const int* srcp = ei;
    const int* dstp = ei + E;

    // ---- workspace map (~215.4 MB peak) ----
    char* ws = (char*)d_ws;
    int* cnt   = (int*)(ws + 0);                 // S*4       = 480,000
    int* base  = (int*)(ws + 480000);            // S*4       = 480,000
    int* ecur  = (int*)(ws + 960000);            // S*4       = 480,000
    int* elist = (int*)(ws + 1440000);           // E*4       = 2,000,000
    int* bsum  = (int*)(ws + 3440000);           // 512*4
    unsigned short* W1t = (unsigned short*)(ws + 3442048);   // 1024x1024
    unsigned short* W2t = (unsigned short*)(ws + 5539200);   // 1536x1024
    unsigned short* r2t = (unsigned short*)(ws + 8684928);   // 512x1024
    unsigned short* W3t = (unsigned short*)(ws + 9733504);   // 384x512
    unsigned short* r3t = (unsigned short*)(ws + 10126720);  // 128x512
    char* arena = ws + 10257792;
    // RA (82,051,072): Xcat (NP x 1024 bf16) -> h2acc (NP x 512 f32)
    unsigned short* Xcat  = (unsigned short*)(arena);
    float*          h2acc = (float*)(arena);
    // RB (82,051,072): h1b (NP x 1024 bf16) -> h2b (NP x 512 bf16) + H3all (NP x 384 bf16)
    unsigned short* h1b   = (unsigned short*)(arena + 82051072);
    unsigned short* h2b   = (unsigned short*)(arena + 82051072);
    unsigned short* H3all = (unsigned short*)(arena + 82051072 + 41025536);
    // RC (41,025,536): H2q (NP x 512 bf16) -> h3root + h3 (NP x 128 f32 each)
    unsigned short* H2q    = (unsigned short*)(arena + 164102144);
    float*          h3root = (float*)(arena + 164102144);
    float*          h3     = (float*)(arena + 164102144 + 20512768);

    // ---- CSR build: count -> scan -> fill ----
    zero_kernel<<<(S / 4 + 255) / 256, 256, 0, stream>>>((float*)cnt, S / 4);
    zero_kernel<<<(S / 4 + 255) / 256, 256, 0, stream>>>((float*)ecur, S / 4);
    count_kernel<<<(E + 255) / 256, 256, 0, stream>>>(dstp, etp, cnt, E);
    scanA<<<NB, 256, 0, stream>>>(cnt, base, bsum, S);
    scanB<<<1, 512, 0, stream>>>(bsum, NB);
    scanC<<<NB, 256, 0, stream>>>(base, bsum, S);
    fill_kernel<<<(E + 255) / 256, 256, 0, stream>>>(srcp, dstp, etp, base, ecur, elist, E);

    // ---- weight transposes (f32 -> bf16, [Nout][K]) ----
    transpose_bf16<<<(768 * 1024 + 255) / 256, 256, 0, stream>>>(W1, W1t, 768, 1024, 1024);
    transpose_bf16<<<(256 * 1024 + 255) / 256, 256, 0, stream>>>(root1, W1t + 768, 256, 1024, 1024);
    for (int r = 0; r < 3; ++r)
        transpose_bf16<<<(1024 * 512 + 255) / 256, 256, 0, stream>>>(
            W2 + (size_t)r * 1024 * 512, W2t + (size_t)r * 512 * 1024, 1024, 512, 1024);
    transpose_bf16<<<(1024 * 512 + 255) / 256, 256, 0, stream>>>(root2, r2t, 1024, 512, 1024);
    for (int r = 0; r < 3; ++r)
        transpose_bf16<<<(512 * 128 + 255) / 256, 256, 0, stream>>>(
            W3 + (size_t)r * 65536, W3t + (size_t)r * 128 * 512, 512, 128, 512);
    transpose_bf16<<<(512 * 128 + 255) / 256, 256, 0, stream>>>(root3, r3t, 512, 128, 512);

    // ---- layer 1: gather-aggregate -> one GEMM ----
    agg1_kernel<<<N, 256, 0, stream>>>(x, base, cnt, elist, Xcat, N);
    gemm_mfma<<<dim3(8, GY), 256, 0, stream>>>(
        Xcat, W1t, b1, h1b, 1024, 1024, 1024, GF_BIAS | GF_RELU | GF_BF16);

    // ---- layer 2: root GEMM -> 3x (GEMM_r -> gather-agg accumulate) ----
    gemm_mfma<<<dim3(4, GY), 256, 0, stream>>>(
        h1b, r2t, b2, h2acc, 512, 1024, 1024, GF_BIAS);
    for (int r = 0; r < 3; ++r) {
        gemm_mfma<<<dim3(4, GY), 256, 0, stream>>>(
            h1b, W2t + (size_t)r * 512 * 1024, nullptr, H2q, 512, 1024, 1024, GF_BF16);
        agg2_kernel<<<N, 128, 0, stream>>>(H2q, h2acc, h2b, base, cnt, elist, r, r == 2);
    }

    // ---- layer 3: one GEMM (384) + root GEMM -> gather-agg ----
    gemm_mfma<<<dim3(3, GY), 256, 0, stream>>>(
        h2b, W3t, nullptr, H3all, 384, 512, 512, GF_BF16);
    gemm_mfma<<<dim3(1, GY), 256, 0, stream>>>(
        h2b, r3t, b3, h3root, 128, 512, 512, GF_BIAS);
    agg3_kernel<<<N, 64, 0, stream>>>(H3all, h3root, h3, base, cnt, elist);

    // ---- FC head + log_softmax (relu fused into load) ----
    head_kernel<<<N / 4, 256, 0, stream>>>(h3, fcw, fcb, out, N);
}

// Round 5
// 705.384 us; speedup vs baseline: 14.9924x; 1.2147x over previous
//
#include <hip/hip_runtime.h>
#include <cstdint>
#include <cstddef>

// ---------------------------------------------------------------------------
// RGCN 3-layer + FC head. bf16 MFMA GEMMs (XCD-stripe-swizzled) + CSR gather
// aggregation (no atomics in hot path). Layer-2/3 weight-concat fused GEMMs.
// Layer-2 fusion needs ~253.8 MB ws -> gated on ws_size with incremental
// fallback (~214.9 MB, proven).
// ---------------------------------------------------------------------------

typedef short bf16x8 __attribute__((ext_vector_type(8)));
typedef float f32x4 __attribute__((ext_vector_type(4)));

#define GF_BIAS 1
#define GF_RELU 2
#define GF_BF16 4

__device__ __forceinline__ unsigned short f2bf(float f) {
    unsigned u = __float_as_uint(f);
    return (unsigned short)((u + 0x7FFFu + ((u >> 16) & 1u)) >> 16);
}
__device__ __forceinline__ float bf2f(unsigned short h) {
    return __uint_as_float((unsigned)h << 16);
}

__global__ __launch_bounds__(256) void zero_kernel(float* __restrict__ p, long n4)
{
    long i = (long)blockIdx.x * 256 + threadIdx.x;
    if (i < n4) ((float4*)p)[i] = make_float4(0.f, 0.f, 0.f, 0.f);
}

__global__ __launch_bounds__(256) void count_kernel(
    const int* __restrict__ dst, const int* __restrict__ et,
    int* __restrict__ cnt, int E)
{
    int e = blockIdx.x * 256 + threadIdx.x;
    if (e < E) atomicAdd(&cnt[dst[e] * 3 + et[e]], 1);
}

// ---- 2-level exclusive scan over S ints ----
__global__ __launch_bounds__(256) void scanA(
    const int* __restrict__ cnt, int* __restrict__ base,
    int* __restrict__ bsum, int S)
{
    __shared__ int sh[256];
    int i = blockIdx.x * 256 + threadIdx.x;
    int v = (i < S) ? cnt[i] : 0;
    sh[threadIdx.x] = v;
    __syncthreads();
#pragma unroll
    for (int off = 1; off < 256; off <<= 1) {
        int t = (threadIdx.x >= off) ? sh[threadIdx.x - off] : 0;
        __syncthreads();
        sh[threadIdx.x] += t;
        __syncthreads();
    }
    if (i < S) base[i] = sh[threadIdx.x] - v;
    if (threadIdx.x == 255) bsum[blockIdx.x] = sh[255];
}

__global__ __launch_bounds__(512) void scanB(int* __restrict__ bsum, int NB)
{
    __shared__ int sh[512];
    int t = threadIdx.x;
    int v = (t < NB) ? bsum[t] : 0;
    sh[t] = v;
    __syncthreads();
#pragma unroll
    for (int off = 1; off < 512; off <<= 1) {
        int u = (t >= off) ? sh[t - off] : 0;
        __syncthreads();
        sh[t] += u;
        __syncthreads();
    }
    if (t < NB) bsum[t] = sh[t] - v;
}

__global__ __launch_bounds__(256) void scanC(
    int* __restrict__ base, const int* __restrict__ bsum, int S)
{
    int i = blockIdx.x * 256 + threadIdx.x;
    if (i < S) base[i] += bsum[blockIdx.x];
}

__global__ __launch_bounds__(256) void fill_kernel(
    const int* __restrict__ src, const int* __restrict__ dst,
    const int* __restrict__ et, const int* __restrict__ base,
    int* __restrict__ ecur, int* __restrict__ elist, int E)
{
    int e = blockIdx.x * 256 + threadIdx.x;
    if (e >= E) return;
    int seg = dst[e] * 3 + et[e];
    int pos = base[seg] + atomicAdd(&ecur[seg], 1);
    elist[pos] = src[e];
}

// transpose + f32->bf16: out[j*ldo + i] = bf16(in[i*C + j]), i<R, j<C
__global__ __launch_bounds__(256) void transpose_bf16(
    const float* __restrict__ in, unsigned short* __restrict__ out,
    int R, int C, int ldo)
{
    int idx = blockIdx.x * 256 + threadIdx.x;
    if (idx >= R * C) return;
    int j = idx / R, i = idx - j * R;
    out[(size_t)j * ldo + i] = f2bf(in[(size_t)i * C + j]);
}

// f32 -> bf16 elementwise, 8 per thread
__global__ __launch_bounds__(256) void conv_bf16(
    const float* __restrict__ s, unsigned short* __restrict__ d, long n8)
{
    long i = (long)blockIdx.x * 256 + threadIdx.x;
    if (i >= n8) return;
    const float* p = s + i * 8;
    float4 a = *(const float4*)p, b = *(const float4*)(p + 4);
    ushort4 o0, o1;
    o0.x = f2bf(a.x); o0.y = f2bf(a.y); o0.z = f2bf(a.z); o0.w = f2bf(a.w);
    o1.x = f2bf(b.x); o1.y = f2bf(b.y); o1.z = f2bf(b.z); o1.w = f2bf(b.w);
    *(ushort4*)(d + i * 8) = o0;
    *(ushort4*)(d + i * 8 + 4) = o1;
}

// dst[i] = i < nsrc ? src[i] : 0
__global__ __launch_bounds__(256) void make_bias(
    float* __restrict__ dst, const float* __restrict__ src, int nsrc, int ntot)
{
    int i = blockIdx.x * 256 + threadIdx.x;
    if (i < ntot) dst[i] = (i < nsrc) ? src[i] : 0.f;
}

// Layer-1 aggregate (gather, bf16 x): block = 4 waves, node n.
__global__ __launch_bounds__(256) void agg1_kernel(
    const unsigned short* __restrict__ xb, const int* __restrict__ base,
    const int* __restrict__ cnt, const int* __restrict__ elist,
    unsigned short* __restrict__ Xcat)
{
    int n = blockIdx.x;
    int w = threadIdx.x >> 6, l = threadIdx.x & 63;
    if (w == 3) {
        *(ushort4*)&Xcat[(size_t)n * 1024 + 768 + l * 4] =
            *(const ushort4*)&xb[(size_t)n * 256 + l * 4];
        return;
    }
    int seg = n * 3 + w;
    int st = base[seg], len = cnt[seg];
    float norm = 1.0f / (float)(len > 0 ? len : 1);
    float4 s = make_float4(0.f, 0.f, 0.f, 0.f);
    for (int i = 0; i < len; ++i) {
        int sx = elist[st + i];
        ushort4 v = *(const ushort4*)&xb[(size_t)sx * 256 + l * 4];
        s.x += bf2f(v.x); s.y += bf2f(v.y); s.z += bf2f(v.z); s.w += bf2f(v.w);
    }
    ushort4 o;
    o.x = f2bf(s.x * norm); o.y = f2bf(s.y * norm);
    o.z = f2bf(s.z * norm); o.w = f2bf(s.w * norm);
    *(ushort4*)&Xcat[(size_t)n * 1024 + w * 256 + l * 4] = o;
}

// Fused layer-2 aggregate: H2all [NP][2048] bf16 (root cols 0..511, rel r at
// 512*(1+r)). h2b[n,c] = bf16(relu(root + sum_r mean_r)). 128 thr, 4 cols ea.
__global__ __launch_bounds__(128) void agg2_fused(
    const unsigned short* __restrict__ H2all, unsigned short* __restrict__ h2b,
    const int* __restrict__ base, const int* __restrict__ cnt,
    const int* __restrict__ elist)
{
    int n = blockIdx.x, t = threadIdx.x;
    ushort4 rv = *(const ushort4*)&H2all[(size_t)n * 2048 + t * 4];
    float4 a = make_float4(bf2f(rv.x), bf2f(rv.y), bf2f(rv.z), bf2f(rv.w));
#pragma unroll
    for (int r = 0; r < 3; ++r) {
        int seg = n * 3 + r;
        int st = base[seg], len = cnt[seg];
        float norm = 1.0f / (float)(len > 0 ? len : 1);
        float4 s = make_float4(0.f, 0.f, 0.f, 0.f);
        for (int i = 0; i < len; ++i) {
            int sx = elist[st + i];
            ushort4 v = *(const ushort4*)&H2all[(size_t)sx * 2048 + 512 * (1 + r) + t * 4];
            s.x += bf2f(v.x); s.y += bf2f(v.y); s.z += bf2f(v.z); s.w += bf2f(v.w);
        }
        a.x += s.x * norm; a.y += s.y * norm; a.z += s.z * norm; a.w += s.w * norm;
    }
    ushort4 o;
    o.x = f2bf(fmaxf(a.x, 0.f)); o.y = f2bf(fmaxf(a.y, 0.f));
    o.z = f2bf(fmaxf(a.z, 0.f)); o.w = f2bf(fmaxf(a.w, 0.f));
    *(ushort4*)&h2b[(size_t)n * 512 + t * 4] = o;
}

// Incremental layer-2 aggregate (fallback path), relation r at a time.
__global__ __launch_bounds__(128) void agg2_inc(
    const unsigned short* __restrict__ H2q, float* __restrict__ h2acc,
    unsigned short* __restrict__ h2b, const int* __restrict__ base,
    const int* __restrict__ cnt, const int* __restrict__ elist, int r, int last)
{
    int n = blockIdx.x, t = threadIdx.x;
    int seg = n * 3 + r;
    int st = base[seg], len = cnt[seg];
    float norm = 1.0f / (float)(len > 0 ? len : 1);
    float4 s = make_float4(0.f, 0.f, 0.f, 0.f);
    for (int i = 0; i < len; ++i) {
        int sx = elist[st + i];
        ushort4 v = *(const ushort4*)&H2q[(size_t)sx * 512 + t * 4];
        s.x += bf2f(v.x); s.y += bf2f(v.y); s.z += bf2f(v.z); s.w += bf2f(v.w);
    }
    float4 a = *(const float4*)&h2acc[(size_t)n * 512 + t * 4];
    a.x += s.x * norm; a.y += s.y * norm; a.z += s.z * norm; a.w += s.w * norm;
    if (!last) {
        *(float4*)&h2acc[(size_t)n * 512 + t * 4] = a;
    } else {
        ushort4 o;
        o.x = f2bf(fmaxf(a.x, 0.f)); o.y = f2bf(fmaxf(a.y, 0.f));
        o.z = f2bf(fmaxf(a.z, 0.f)); o.w = f2bf(fmaxf(a.w, 0.f));
        *(ushort4*)&h2b[(size_t)n * 512 + t * 4] = o;
    }
}

// Layer-3 aggregate: H3cat [NP][512] bf16 (root cols 0..127, rel r at 128*(1+r))
// h3[n,c] = root + sum_r mean_r   (relu applied in head). 1 wave, 2 cols/lane.
__global__ __launch_bounds__(64) void agg3_kernel(
    const unsigned short* __restrict__ H3cat, float* __restrict__ h3,
    const int* __restrict__ base, const int* __restrict__ cnt,
    const int* __restrict__ elist)
{
    int n = blockIdx.x;
    int l = threadIdx.x;
    ushort2 rt = *(const ushort2*)&H3cat[(size_t)n * 512 + l * 2];
    float s0 = bf2f(rt.x), s1 = bf2f(rt.y);
#pragma unroll
    for (int r = 0; r < 3; ++r) {
        int seg = n * 3 + r;
        int st = base[seg], len = cnt[seg];
        float norm = 1.0f / (float)(len > 0 ? len : 1);
        float t0 = 0.f, t1 = 0.f;
        for (int i = 0; i < len; ++i) {
            int sx = elist[st + i];
            ushort2 v = *(const ushort2*)&H3cat[(size_t)sx * 512 + 128 * (1 + r) + l * 2];
            t0 += bf2f(v.x); t1 += bf2f(v.y);
        }
        s0 += t0 * norm; s1 += t1 * norm;
    }
    float2 o; o.x = s0; o.y = s1;
    *(float2*)&h3[(size_t)n * 128 + l * 2] = o;
}

// ---------------------------------------------------------------------------
// MFMA GEMM, XCD-stripe swizzled 1-D grid. C = A[M,K] @ Bt[Nout,K]^T.
// 128x128 tile, BK=64, 4 waves, XOR-swizzled LDS, global_load_lds x16.
// Launch with grid = GX*GY (GX = Nout/128 = 1<<lgGX, GY = Mpad/128).
// ---------------------------------------------------------------------------
__global__ __launch_bounds__(256) void gemm_mfma(
    const unsigned short* __restrict__ A, const unsigned short* __restrict__ Bt,
    const float* __restrict__ bias, void* __restrict__ C,
    int Nout, int K, int ldbt, int flags, int lgGX)
{
    __shared__ short __align__(16) As[8192];
    __shared__ short __align__(16) Bs[8192];
    const int tid = threadIdx.x;
    const int w = tid >> 6, l = tid & 63;

    // bijective XCD-stripe swizzle: each XCD gets a contiguous id2 range,
    // column-block fastest -> A row-panel reused across all GX col-blocks.
    const int nblk = (int)gridDim.x;
    const int q = nblk >> 3, rem = nblk & 7;
    const int xcd = blockIdx.x & 7, local = blockIdx.x >> 3;
    const int id2 = xcd * q + (xcd < rem ? xcd : rem) + local;
    const int row0 = (id2 >> lgGX) * 128;
    const int col0 = (id2 & ((1 << lgGX) - 1)) * 128;

    const int wm = w >> 1, wn = w & 1;
    const int lr = l >> 3, lc = l & 7;

    f32x4 acc[4][4];
#pragma unroll
    for (int i = 0; i < 4; ++i)
#pragma unroll
        for (int j = 0; j < 4; ++j) acc[i][j] = (f32x4){0.f, 0.f, 0.f, 0.f};

    for (int k0 = 0; k0 < K; k0 += 64) {
        __syncthreads();
#pragma unroll
        for (int i = 0; i < 4; ++i) {
            const int c  = i * 4 + w;
            const int r  = c * 8 + lr;
            const int c8 = lc ^ (r & 7);
            __builtin_amdgcn_global_load_lds(
                (const __attribute__((address_space(1))) void*)
                    (A + (size_t)(row0 + r) * K + k0 + c8 * 8),
                (__attribute__((address_space(3))) void*)(As + c * 512),
                16, 0, 0);
            __builtin_amdgcn_global_load_lds(
                (const __attribute__((address_space(1))) void*)
                    (Bt + (size_t)(col0 + r) * ldbt + k0 + c8 * 8),
                (__attribute__((address_space(3))) void*)(Bs + c * 512),
                16, 0, 0);
        }
        __syncthreads();
#pragma unroll
        for (int ks = 0; ks < 2; ++ks) {
            bf16x8 af[4], bfv[4];
#pragma unroll
            for (int mf = 0; mf < 4; ++mf) {
                int r = wm * 64 + mf * 16 + (l & 15);
                int byt = (r * 128 + ks * 64 + (l >> 4) * 16) ^ ((r & 7) << 4);
                af[mf] = *(const bf16x8*)((const char*)As + byt);
            }
#pragma unroll
            for (int nf = 0; nf < 4; ++nf) {
                int r = wn * 64 + nf * 16 + (l & 15);
                int byt = (r * 128 + ks * 64 + (l >> 4) * 16) ^ ((r & 7) << 4);
                bfv[nf] = *(const bf16x8*)((const char*)Bs + byt);
            }
#pragma unroll
            for (int mf = 0; mf < 4; ++mf)
#pragma unroll
                for (int nf = 0; nf < 4; ++nf)
                    acc[mf][nf] = __builtin_amdgcn_mfma_f32_16x16x32_bf16(
                        af[mf], bfv[nf], acc[mf][nf], 0, 0, 0);
        }
    }

    const int lrow = (l >> 4) * 4;
    const int lcol = l & 15;
#pragma unroll
    for (int mf = 0; mf < 4; ++mf) {
#pragma unroll
        for (int nf = 0; nf < 4; ++nf) {
            int col = col0 + wn * 64 + nf * 16 + lcol;
            float bv = (flags & GF_BIAS) ? bias[col] : 0.f;
#pragma unroll
            for (int rr = 0; rr < 4; ++rr) {
                int row = row0 + wm * 64 + mf * 16 + lrow + rr;
                float v = acc[mf][nf][rr] + bv;
                if (flags & GF_RELU) v = fmaxf(v, 0.f);
                size_t idx = (size_t)row * Nout + col;
                if (flags & GF_BF16) ((unsigned short*)C)[idx] = f2bf(v);
                else                 ((float*)C)[idx] = v;
            }
        }
    }
}

// logits = relu(h3) @ fcw + fcb; out = log_softmax. One wave per row.
__global__ __launch_bounds__(256) void head_kernel(
    const float* __restrict__ h3, const float* __restrict__ fcw,
    const float* __restrict__ fcb, float* __restrict__ out, int M)
{
    __shared__ float sh[4][128];
    int wid = threadIdx.x >> 6, lane = threadIdx.x & 63;
    int row = blockIdx.x * 4 + wid;
    sh[wid][lane]      = fmaxf(h3[(size_t)row * 128 + lane], 0.f);
    sh[wid][64 + lane] = fmaxf(h3[(size_t)row * 128 + 64 + lane], 0.f);
    __syncthreads();
    float logit = 0.f;
    if (lane < 21) {
        logit = fcb[lane];
#pragma unroll
        for (int k = 0; k < 128; ++k) logit += sh[wid][k] * fcw[k * 21 + lane];
    }
    float v = (lane < 21) ? logit : -INFINITY;
#pragma unroll
    for (int off = 32; off; off >>= 1) v = fmaxf(v, __shfl_xor(v, off));
    float mx = v;
    float ex = (lane < 21) ? expf(logit - mx) : 0.f;
#pragma unroll
    for (int off = 32; off; off >>= 1) ex += __shfl_xor(ex, off);
    if (lane < 21) out[(size_t)row * 21 + lane] = logit - mx - logf(ex);
}

extern "C" void kernel_launch(void* const* d_in, const int* in_sizes, int n_in,
                              void* d_out, int out_size, void* d_ws, size_t ws_size,
                              hipStream_t stream)
{
    const float* x     = (const float*)d_in[0];
    const int*   ei    = (const int*)d_in[1];
    const int*   etp   = (const int*)d_in[2];
    const float* W1    = (const float*)d_in[3];
    const float* root1 = (const float*)d_in[4];
    const float* b1    = (const float*)d_in[5];
    const float* W2    = (const float*)d_in[6];
    const float* root2 = (const float*)d_in[7];
    const float* b2    = (const float*)d_in[8];
    const float* W3    = (const float*)d_in[9];
    const float* root3 = (const float*)d_in[10];
    const float* b3    = (const float*)d_in[11];
    const float* fcw   = (const float*)d_in[12];
    const float* fcb   = (const float*)d_in[13];
    float* out = (float*)d_out;
    (void)n_in; (void)out_size;

    const int N  = in_sizes[0] / 256;            // 40000
    const int E  = in_sizes[2];                  // 500000
    const int S  = N * 3;
    const int NP = (N + 127) / 128 * 128;        // 40064
    const int GY = NP / 128;                     // 313
    const int NB = (S + 255) / 256;
    const int* srcp = ei;
    const int* dstp = ei + E;

    const size_t SZ_X1024 = (size_t)NP * 1024 * 2;   // 82,051,072
    const size_t SZ_X512b = (size_t)NP * 512 * 2;    // 41,025,536
    const size_t SZ_X2048 = (size_t)NP * 2048 * 2;   // 164,102,144
    const size_t SZ_XB    = (size_t)NP * 256 * 2;    // 20,512,768
    const size_t SZ_H3    = (size_t)NP * 128 * 4;    // 20,512,768

    // ---- fixed region (both paths) ----
    char* ws = (char*)d_ws;
    int*            cnt   = (int*)(ws + 0);                  //   480,256
    int*            base  = (int*)(ws + 480256);             //   480,256
    int*            elist = (int*)(ws + 960512);             // 2,000,000
    float*          b2cat = (float*)(ws + 2960512);          //     8,192
    float*          b3cat = (float*)(ws + 2968704);          //     2,048
    unsigned short* W3cat = (unsigned short*)(ws + 2970752); //   524,288
    unsigned short* W2cat = (unsigned short*)(ws + 3495040); // 4,194,304
    const size_t fixed_end = 7689344;                        // (pad to 4096)
    const size_t FUSED_NEED = 7692288 + SZ_X2048 + SZ_X1024; // 253,845,504
    const bool fused = ws_size >= FUSED_NEED;

    char* arena;
    unsigned short *W1t, *xb, *Xcat, *h1b, *H2all, *H2q, *h2b, *H3cat;
    float *h2acc, *h3;
    if (fused) {
        arena = ws + 7692288;
        Xcat  = (unsigned short*)(arena);
        W1t   = (unsigned short*)(arena + SZ_X1024);                  // dead before GEMM2
        xb    = (unsigned short*)(arena + SZ_X1024 + 2097152);
        h1b   = (unsigned short*)(arena + SZ_X2048);
        H2all = (unsigned short*)(arena);                             // after GEMM1
        h2b   = (unsigned short*)(arena + SZ_X2048);                  // over h1b
        H3cat = (unsigned short*)(arena);                             // after agg2
        h3    = (float*)(arena + SZ_X512b);
        H2q = nullptr; h2acc = nullptr;
    } else {
        W1t   = (unsigned short*)(ws + fixed_end);                    // 2,097,152
        arena = ws + fixed_end + 2097152 + 2944;                      // align 4096
        Xcat  = (unsigned short*)(arena);
        h2acc = (float*)(arena);                                      // after GEMM1
        h1b   = (unsigned short*)(arena + SZ_X1024);
        h2b   = (unsigned short*)(arena + SZ_X1024);                  // over h1b
        H3cat = (unsigned short*)(arena + SZ_X1024 + SZ_X512b);
        xb    = (unsigned short*)(arena + 2 * SZ_X1024);              // pre-layer2 only
        H2q   = (unsigned short*)(arena + 2 * SZ_X1024);
        h3    = (float*)(arena + 2 * SZ_X1024);                       // after agg2
        H2all = nullptr;
    }
    int* ecur = (int*)(arena);          // CSR-build scratch, pre-agg1 only
    int* bsum = (int*)(arena + 480256);

    // ---- CSR build ----
    zero_kernel<<<(S * 4 / 16 + 255) / 256, 256, 0, stream>>>((float*)cnt, S * 4 / 16);
    zero_kernel<<<(S * 4 / 16 + 255) / 256, 256, 0, stream>>>((float*)ecur, S * 4 / 16);
    count_kernel<<<(E + 255) / 256, 256, 0, stream>>>(dstp, etp, cnt, E);
    scanA<<<NB, 256, 0, stream>>>(cnt, base, bsum, S);
    scanB<<<1, 512, 0, stream>>>(bsum, NB);
    scanC<<<NB, 256, 0, stream>>>(base, bsum, S);
    fill_kernel<<<(E + 255) / 256, 256, 0, stream>>>(srcp, dstp, etp, base, ecur, elist, E);

    // ---- weights: transpose to [Nout][K] bf16; concat biases ----
    transpose_bf16<<<(768 * 1024 + 255) / 256, 256, 0, stream>>>(W1, W1t, 768, 1024, 1024);
    transpose_bf16<<<(256 * 1024 + 255) / 256, 256, 0, stream>>>(root1, W1t + 768, 256, 1024, 1024);
    transpose_bf16<<<(1024 * 512 + 255) / 256, 256, 0, stream>>>(root2, W2cat, 1024, 512, 1024);
    for (int r = 0; r < 3; ++r)
        transpose_bf16<<<(1024 * 512 + 255) / 256, 256, 0, stream>>>(
            W2 + (size_t)r * 524288, W2cat + (size_t)(1 + r) * 524288, 1024, 512, 1024);
    transpose_bf16<<<(512 * 128 + 255) / 256, 256, 0, stream>>>(root3, W3cat, 512, 128, 512);
    for (int r = 0; r < 3; ++r)
        transpose_bf16<<<(512 * 128 + 255) / 256, 256, 0, stream>>>(
            W3 + (size_t)r * 65536, W3cat + (size_t)(1 + r) * 65536, 512, 128, 512);
    make_bias<<<8, 256, 0, stream>>>(b2cat, b2, 512, 2048);
    make_bias<<<2, 256, 0, stream>>>(b3cat, b3, 128, 512);
    conv_bf16<<<(int)(((long)N * 32 + 255) / 256), 256, 0, stream>>>(x, xb, (long)N * 32);

    // ---- layer 1 ----
    agg1_kernel<<<N, 256, 0, stream>>>(xb, base, cnt, elist, Xcat);
    gemm_mfma<<<8 * GY, 256, 0, stream>>>(
        Xcat, W1t, b1, h1b, 1024, 1024, 1024, GF_BIAS | GF_RELU | GF_BF16, 3);

    // ---- layer 2 ----
    if (fused) {
        gemm_mfma<<<16 * GY, 256, 0, stream>>>(
            h1b, W2cat, b2cat, H2all, 2048, 1024, 1024, GF_BIAS | GF_BF16, 4);
        agg2_fused<<<N, 128, 0, stream>>>(H2all, h2b, base, cnt, elist);
    } else {
        gemm_mfma<<<4 * GY, 256, 0, stream>>>(
            h1b, W2cat, b2, h2acc, 512, 1024, 1024, GF_BIAS, 2);
        for (int r = 0; r < 3; ++r) {
            gemm_mfma<<<4 * GY, 256, 0, stream>>>(
                h1b, W2cat + (size_t)(1 + r) * 524288, nullptr, H2q, 512, 1024, 1024, GF_BF16, 2);
            agg2_inc<<<N, 128, 0, stream>>>(H2q, h2acc, h2b, base, cnt, elist, r, r == 2);
        }
    }

    // ---- layer 3 (fused root+relations) ----
    gemm_mfma<<<4 * GY, 256, 0, stream>>>(
        h2b, W3cat, b3cat, H3cat, 512, 512, 512, GF_BIAS | GF_BF16, 2);
    agg3_kernel<<<N, 64, 0, stream>>>(H3cat, h3, base, cnt, elist);

    // ---- FC head + log_softmax ----
    head_kernel<<<N / 4, 256, 0, stream>>>(h3, fcw, fcb, out, N);
}